// Round 15
// baseline (548.305 us; speedup 1.0000x reference)
//
#include <hip/hip_runtime.h>
#include <hip/hip_bf16.h>
#include <cstdint>
#include <cstddef>

// ---------------------------------------------------------------------------
// IPAttnProcessor: out = (softmax(QK^T)V + softmax(QKip^T)Vip) @ Wo + bo + residual
// B=8 SQ=4096 C=1280 CAD=2048 H=20 D=64 TXT=77 NT=4 IP_SCALE=1
// r15: GEMM was LDS-read-BW-bound (96KiB/K-tile @85B/cyc = 1150cy vs MFMA
// 1240cy -> 27% MfmaUtil across all schedules). B now bypasses LDS: fragments
// loaded global->reg (L2-resident weights), double-buffered by tile parity,
// prefetched 2 tiles ahead; LDS = A-ring4 only (64KB). vmcnt(6) counted waits.
// ---------------------------------------------------------------------------

typedef __bf16 bf16_t;
typedef __bf16 bf16x8 __attribute__((ext_vector_type(8)));
typedef __bf16 bf16x4 __attribute__((ext_vector_type(4)));
typedef float  f32x4  __attribute__((ext_vector_type(4)));
typedef unsigned int u32x4 __attribute__((ext_vector_type(4)));

using as3_void  = __attribute__((address_space(3))) void;
using as1_cvoid = const __attribute__((address_space(1))) void;

#define TXT_ 77

__device__ __forceinline__ bf16x8 ld16(const void* p) {
  u32x4 v = *(const u32x4*)p;
  return __builtin_bit_cast(bf16x8, v);
}

// ---------------------------------------------------------------------------
// GEMM body: C[M,N] = A[M,K] @ Bt[N,K]^T. 256x256 tile, BK=32, 512 thr
// (8 waves = 2M x 4N, per-wave 128x64, acc[8][4] in AGPR).
// LDS 64KB: A ring4 only (4 x 16KB, r4-verified 0-conflict swizzle).
// B fragments: global->reg b128 loads (wave = 16 rows x 64B contiguous, L2),
// two named reg sets bA/bB (tile parity), prefetch t+2 issued AFTER the
// MFMAs that consume the set (no WAR hazard). Tile-end vmcnt(6) retires
// exactly A(t+1)+B(t+1); drain at NTk-2. Per-CU per-tile LDS reads drop
// 96KiB -> 64KiB (753cy) < MFMA (1240cy).
// EPI=0: LDS-packed bf16 epilogue, two 128-row passes (512B full lines).
// EPI=2: f32 + bias[col] + bf16 residual.
// ---------------------------------------------------------------------------
template <int EPI>
__device__ __forceinline__ void gemm256_body(
    char* smem, const bf16_t* __restrict__ A, const bf16_t* __restrict__ Bt,
    void* __restrict__ Cout, int g, int ntn, int N, int K,
    const float* __restrict__ bias, const bf16_t* __restrict__ residual)
{
  const int tid = threadIdx.x, lane = tid & 63, wid = tid >> 6;
  const int wm = wid >> 2, wn = wid & 3;

  const long bm = (long)(g / ntn) * 256;
  const long bn = (long)(g % ntn) * 256;
  const int NTk = K >> 5;

  const int srow = lane >> 2;
  const int scol = ((lane & 3) ^ ((lane >> 3) & 3)) * 8;

  auto stageA = [&](int t) {
    const int buf = t & 3;
    const long k0 = (long)t << 5;
#pragma unroll
    for (int j = 0; j < 2; ++j) {
      const int ci = j * 8 + wid;
      const bf16_t* gp = A + (bm + ci * 16 + srow) * (long)K + k0 + scol;
      __builtin_amdgcn_global_load_lds((as1_cvoid*)gp,
          (as3_void*)(smem + buf * 16384 + ci * 1024), 16, 0, 0);
    }
  };

  const int l15 = lane & 15, kq = lane >> 4;
  const int rc16 = (kq ^ ((l15 >> 1) & 3)) << 4;

  // B fragment global base: row = bn + wn*64 + n*16 + l15, 16B chunk kq
  const bf16_t* bbase = Bt + (bn + wn * 64 + l15) * (long)K + kq * 8;

  auto loadB = [&](int t, bf16x8 (&bq)[4]) {
    const long k0 = (long)t << 5;
#pragma unroll
    for (int n = 0; n < 4; ++n)
      bq[n] = ld16(bbase + (long)n * 16 * K + k0);
  };

  f32x4 acc[8][4] = {};
  bf16x8 bA[4], bB[4];

  // prologue: A0,A1 staged; B0->bA, B1->bB. Retire oldest 8 (A0,A1,B0).
  stageA(0); stageA(1);
  loadB(0, bA); loadB(1, bB);
  asm volatile("s_waitcnt vmcnt(4)" ::: "memory");
  __builtin_amdgcn_s_barrier();

  auto iter = [&](int t, bf16x8 (&bcur)[4]) {
    const char* sa = smem + (t & 3) * 16384;
    const bool pf = (t + 2 < NTk);
    bf16x8 afr[4];
#pragma unroll
    for (int m = 0; m < 4; ++m)
      afr[m] = ld16(sa + (wm * 128 + m * 16 + l15) * 64 + rc16);
    if (pf) stageA(t + 2);
    __builtin_amdgcn_s_setprio(1);
#pragma unroll
    for (int m = 0; m < 4; ++m)
#pragma unroll
      for (int n = 0; n < 4; ++n)
        acc[m][n] = __builtin_amdgcn_mfma_f32_16x16x32_bf16(afr[m], bcur[n], acc[m][n], 0, 0, 0);
    __builtin_amdgcn_s_setprio(0);
#pragma unroll
    for (int m = 0; m < 4; ++m)
      afr[m] = ld16(sa + (wm * 128 + (m + 4) * 16 + l15) * 64 + rc16);
    __builtin_amdgcn_s_setprio(1);
#pragma unroll
    for (int m = 0; m < 4; ++m)
#pragma unroll
      for (int n = 0; n < 4; ++n)
        acc[m + 4][n] = __builtin_amdgcn_mfma_f32_16x16x32_bf16(afr[m], bcur[n], acc[m + 4][n], 0, 0, 0);
    __builtin_amdgcn_s_setprio(0);
    if (pf) loadB(t + 2, bcur);   // after last use of bcur this tile
    // tile-end: retire A(t+1)+B(t+1); leave [A(t+2):2, B(t+2):4] in flight
    if (t == NTk - 2)      asm volatile("s_waitcnt vmcnt(0)" ::: "memory");
    else if (t < NTk - 1)  asm volatile("s_waitcnt vmcnt(6)" ::: "memory");
    __builtin_amdgcn_s_barrier();
  };

  for (int t = 0; t < NTk; t += 2) {   // NTk even for K=1280 (40) and 2048 (64)
    iter(t, bA);
    iter(t + 1, bB);
  }

  const int orow0 = (lane >> 4) << 2;
  if constexpr (EPI == 0) {
    // LDS-packed epilogue, two 128-row passes ([128][256] bf16 = 64KB).
    bf16_t* cl = (bf16_t*)smem;
    const int rr = tid >> 5, cc = tid & 31;
#pragma unroll
    for (int h = 0; h < 2; ++h) {
      __syncthreads();
      if (wm == h) {
#pragma unroll
        for (int m = 0; m < 8; ++m)
#pragma unroll
          for (int n = 0; n < 4; ++n)
#pragma unroll
            for (int r = 0; r < 4; ++r)
              cl[(m * 16 + orow0 + r) * 256 + wn * 64 + n * 16 + l15] =
                  (bf16_t)acc[m][n][r];
      }
      __syncthreads();
#pragma unroll
      for (int s = 0; s < 8; ++s) {
        const int row = s * 16 + rr;
        const u32x4 v = *(const u32x4*)(cl + row * 256 + cc * 8);
        *(u32x4*)((bf16_t*)Cout + (bm + h * 128 + row) * (long)N + bn + cc * 8) = v;
      }
    }
  } else {
#pragma unroll
    for (int m = 0; m < 8; ++m) {
#pragma unroll
      for (int n = 0; n < 4; ++n) {
        const long col = bn + wn * 64 + n * 16 + l15;
#pragma unroll
        for (int r = 0; r < 4; ++r) {
          const long row = bm + wm * 128 + m * 16 + orow0 + r;
          ((float*)Cout)[row * N + col] =
              acc[m][n][r] + bias[col] + (float)residual[row * N + col];
        }
      }
    }
  }
}

// GEMM1 + projections fused in one dispatch (680 blocks):
//   0-639:   Q = hs_bf16 @ Wq    (XCD-chunked swizzle over 640)
//   640-669: K|V = a_txt(768 pad) @ [Wk|Wv]   (3x10 tiles, K=2048)
//   670-679: Kip|Vip = a_ip(256 pad) @ [Wk_ip|Wv_ip] (1x10 tiles)
__global__ __launch_bounds__(512, 2)
void gemm1_fused(const bf16_t* __restrict__ hsb, const bf16_t* __restrict__ Wq_t,
                 bf16_t* __restrict__ qb,
                 const bf16_t* __restrict__ a_txt, const bf16_t* __restrict__ Wkv_t,
                 bf16_t* __restrict__ kv_txt,
                 const bf16_t* __restrict__ a_ip, const bf16_t* __restrict__ Wip_t,
                 bf16_t* __restrict__ kv_ip)
{
  __shared__ __align__(16) char smem[65536];
  const int bid = blockIdx.x;
  const bf16_t *A, *Bt;
  bf16_t* C;
  int g, ntn, N, K;
  if (bid < 640) {
    g = (bid & 7) * 80 + (bid >> 3);   // bijective on [0,640)
    A = hsb; Bt = Wq_t; C = qb; ntn = 5; N = 1280; K = 1280;
  } else if (bid < 670) {
    g = bid - 640; A = a_txt; Bt = Wkv_t; C = kv_txt; ntn = 10; N = 2560; K = 2048;
  } else {
    g = bid - 670; A = a_ip; Bt = Wip_t; C = kv_ip; ntn = 10; N = 2560; K = 2048;
  }
  gemm256_body<0>(smem, A, Bt, C, g, ntn, N, K, nullptr, nullptr);
}

// GEMM2: out = attn @ Wo + bo + residual(bf16), 640 blocks, XCD swizzle.
__global__ __launch_bounds__(512, 2)
void gemm2(const bf16_t* __restrict__ A, const bf16_t* __restrict__ Bt,
           float* __restrict__ Cout, const float* __restrict__ bias,
           const bf16_t* __restrict__ residual)
{
  __shared__ __align__(16) char smem[65536];
  const int bid = blockIdx.x;
  const int g = (bid & 7) * 80 + (bid >> 3);
  gemm256_body<2>(smem, A, Bt, Cout, g, 5, 1280, 1280, bias, residual);
}

// ---------------------------------------------------------------------------
// Fused attention (r8-unchanged; writes in-place over Q).
// ---------------------------------------------------------------------------
__global__ __launch_bounds__(256, 3)
void attn_fused(const bf16_t* __restrict__ q, const bf16_t* __restrict__ kvt,
                const bf16_t* __restrict__ kvip, bf16_t* __restrict__ outp)
{
  __shared__ __align__(16) bf16_t K_lds[80 * 64];
  __shared__ __align__(16) bf16_t Kip_lds[16 * 64];
  __shared__ __align__(16) bf16_t Vt_lds[64 * 128];
  __shared__ __align__(16) bf16_t P_lds[4][16 * 128];

  const int tid = threadIdx.x, lane = tid & 63, wid = tid >> 6;
  const int h = blockIdx.y, b = blockIdx.z;
  const int kvcol = h << 6;

  for (int idx = tid; idx < 640; idx += 256) {
    const int j = idx >> 3, c = idx & 7;
    bf16x8 v = {};
    if (j < TXT_) v = ld16(kvt + (long)(b * 80 + j) * 2560 + kvcol + c * 8);
    *(bf16x8*)((char*)K_lds + j * 128 + ((c ^ (j & 7)) << 4)) = v;
  }
  if (tid < 128) {
    const int j = tid >> 3, c = tid & 7;
    bf16x8 v = {};
    if (j < 4) v = ld16(kvip + (long)(b * 4 + j) * 2560 + kvcol + c * 8);
    *(bf16x8*)((char*)Kip_lds + j * 128 + ((c ^ (j & 7)) << 4)) = v;
  }
  for (int idx = tid; idx < 1024; idx += 256) {
    const int key = idx >> 3, c = idx & 7;
    bf16x8 v = {};
    if (key < TXT_)
      v = ld16(kvt + (long)(b * 80 + key) * 2560 + 1280 + kvcol + c * 8);
    else if (key >= 96 && key < 100)
      v = ld16(kvip + (long)(b * 4 + key - 96) * 2560 + 1280 + kvcol + c * 8);
#pragma unroll
    for (int e = 0; e < 8; ++e) {
      const int d = c * 8 + e;
      *(bf16_t*)((char*)Vt_lds + d * 256 + ((key * 2) ^ ((d & 7) << 4))) = v[e];
    }
  }
  for (int idx = tid; idx < 1024; idx += 256)
    *(bf16x8*)((char*)P_lds + idx * 16) = (bf16x8){};
  __syncthreads();

  const int l15 = lane & 15, hi = lane >> 4;
  const int dblk = hi << 3;
  const int prow0 = hi << 2;
  const float scale = 0.125f;
  char* const pw = (char*)P_lds[wid];

  const long qrow0 = (long)b * 4096 + ((long)blockIdx.x << 8) + (wid << 6);
  bf16x8 qf[4][2];
#pragma unroll
  for (int ms = 0; ms < 4; ++ms) {
    const bf16_t* qp = q + (qrow0 + ms * 16 + l15) * 1280 + kvcol;
    qf[ms][0] = ld16(qp + dblk);
    qf[ms][1] = ld16(qp + 32 + dblk);
  }

#pragma unroll
  for (int ms = 0; ms < 4; ++ms) {
    f32x4 sc[5];
#pragma unroll
    for (int t = 0; t < 5; ++t) {
      const int j = (t << 4) + l15;
      const bf16x8 k0 = ld16((char*)K_lds + j * 128 + ((hi ^ (j & 7)) << 4));
      const bf16x8 k1 = ld16((char*)K_lds + j * 128 + (((4 + hi) ^ (j & 7)) << 4));
      f32x4 z = {0.f, 0.f, 0.f, 0.f};
      z = __builtin_amdgcn_mfma_f32_16x16x32_bf16(qf[ms][0], k0, z, 0, 0, 0);
      z = __builtin_amdgcn_mfma_f32_16x16x32_bf16(qf[ms][1], k1, z, 0, 0, 0);
      sc[t] = z;
    }
#pragma unroll
    for (int t = 0; t < 5; ++t) {
      const bool valid = ((t << 4) + l15) < TXT_;
#pragma unroll
      for (int r = 0; r < 4; ++r)
        sc[t][r] = valid ? sc[t][r] * scale : -1e30f;
    }

#pragma unroll
    for (int r = 0; r < 4; ++r) {
      float m = sc[0][r];
#pragma unroll
      for (int t = 1; t < 5; ++t) m = fmaxf(m, sc[t][r]);
      m = fmaxf(m, __shfl_xor(m, 1));
      m = fmaxf(m, __shfl_xor(m, 2));
      m = fmaxf(m, __shfl_xor(m, 4));
      m = fmaxf(m, __shfl_xor(m, 8));
      float l = 0.f;
#pragma unroll
      for (int t = 0; t < 5; ++t) { const float p = __expf(sc[t][r] - m); sc[t][r] = p; l += p; }
      l += __shfl_xor(l, 1);
      l += __shfl_xor(l, 2);
      l += __shfl_xor(l, 4);
      l += __shfl_xor(l, 8);
      const float inv = 1.f / l;
      const int row = prow0 + r;
#pragma unroll
      for (int t = 0; t < 5; ++t)
        *(bf16_t*)(pw + row * 256 + ((((t << 4) + l15) * 2) ^ ((row & 7) << 4))) =
            (bf16_t)(sc[t][r] * inv);
    }

    {
      const bf16x8 ki0 = ld16((char*)Kip_lds + l15 * 128 + ((hi ^ (l15 & 7)) << 4));
      const bf16x8 ki1 = ld16((char*)Kip_lds + l15 * 128 + (((4 + hi) ^ (l15 & 7)) << 4));
      f32x4 z = {0.f, 0.f, 0.f, 0.f};
      z = __builtin_amdgcn_mfma_f32_16x16x32_bf16(qf[ms][0], ki0, z, 0, 0, 0);
      z = __builtin_amdgcn_mfma_f32_16x16x32_bf16(qf[ms][1], ki1, z, 0, 0, 0);
      const bool vip = l15 < 4;
#pragma unroll
      for (int r = 0; r < 4; ++r) {
        const float s = vip ? z[r] * scale : -1e30f;
        float m = s;
        m = fmaxf(m, __shfl_xor(m, 1));
        m = fmaxf(m, __shfl_xor(m, 2));
        m = fmaxf(m, __shfl_xor(m, 4));
        m = fmaxf(m, __shfl_xor(m, 8));
        const float p = __expf(s - m);
        float l = p;
        l += __shfl_xor(l, 1);
        l += __shfl_xor(l, 2);
        l += __shfl_xor(l, 4);
        l += __shfl_xor(l, 8);
        const int row = prow0 + r;
        *(bf16_t*)(pw + row * 256 + (((96 + l15) * 2) ^ ((row & 7) << 4))) =
            (bf16_t)(p * (1.f / l));
      }
    }

    f32x4 o[4] = {};
#pragma unroll
    for (int s = 0; s < 4; ++s) {
      const bf16x8 pa =
          ld16(pw + l15 * 256 + ((((s << 2) + hi) << 4) ^ ((l15 & 7) << 4)));
#pragma unroll
      for (int n = 0; n < 4; ++n) {
        const int d = (n << 4) + l15;
        const bf16x8 vb =
            ld16((char*)Vt_lds + d * 256 + ((((s << 2) + hi) << 4) ^ ((d & 7) << 4)));
        o[n] = __builtin_amdgcn_mfma_f32_16x16x32_bf16(pa, vb, o[n], 0, 0, 0);
      }
    }

    const long orow = qrow0 + ms * 16 + prow0;
#pragma unroll
    for (int n = 0; n < 4; ++n)
#pragma unroll
      for (int r = 0; r < 4; ++r)
        outp[(orow + r) * 1280 + kvcol + (n << 4) + l15] = (bf16_t)o[n][r];
  }
}

// ---------------------------------------------------------------------------
// prep: merged cvt_bf16 (blocks 0-40959) + weight transpose (40960-56319)
// + pack_enc with padding (56320-58367). Valid ip rows: 32 (=B*NT).
// ---------------------------------------------------------------------------
__global__ __launch_bounds__(256)
void prep(const float* __restrict__ hs, bf16_t* __restrict__ hsb,
          const float* __restrict__ Wq, const float* __restrict__ Wo,
          const float* __restrict__ Wk, const float* __restrict__ Wv,
          const float* __restrict__ Wki, const float* __restrict__ Wvi,
          bf16_t* __restrict__ Wq_t, bf16_t* __restrict__ Wo_t,
          bf16_t* __restrict__ Wkv_t, bf16_t* __restrict__ Wip_t,
          const float* __restrict__ enc, bf16_t* __restrict__ a_txt,
          bf16_t* __restrict__ a_ip)
{
  __shared__ float tile[32][33];
  const int bid = blockIdx.x, tid = threadIdx.x;

  if (bid < 40960) {                       // hs fp32 -> bf16 (41943040 elems)
    const long i = ((long)bid * 256 + tid) * 4;
    const float4 v = *(const float4*)(hs + i);
    bf16x4 r;
    r[0] = (bf16_t)v.x; r[1] = (bf16_t)v.y; r[2] = (bf16_t)v.z; r[3] = (bf16_t)v.w;
    *(bf16x4*)(hsb + i) = r;
  } else if (bid < 56320) {                // weight transpose+cvt (6 weights)
    const int idx = bid - 40960;
    const int z = idx / 2560, rem = idx % 2560;
    const int kx = rem & 63, ny = rem >> 6; // 64 k-tiles x 40 n-tiles
    const float* in;
    bf16_t* out;
    int K;
    switch (z) {
      case 0:  in = Wq;  out = Wq_t;                      K = 1280; break;
      case 1:  in = Wo;  out = Wo_t;                      K = 1280; break;
      case 2:  in = Wk;  out = Wkv_t;                     K = 2048; break;
      case 3:  in = Wv;  out = Wkv_t + (long)1280 * 2048; K = 2048; break;
      case 4:  in = Wki; out = Wip_t;                     K = 2048; break;
      default: in = Wvi; out = Wip_t + (long)1280 * 2048; K = 2048; break;
    }
    const int k0 = kx * 32, n0 = ny * 32;
    if (k0 < K) {
      const int tx = tid & 31, ty = tid >> 5;
      for (int i = ty; i < 32; i += 8)
        tile[i][tx] = in[(long)(k0 + i) * 1280 + n0 + tx];
      __syncthreads();
      for (int i = ty; i < 32; i += 8)
        out[(long)(n0 + i) * K + k0 + tx] = (bf16_t)tile[tx][i];
    }
  } else {                                 // encoder pack + zero-pad
    const long t4 = ((long)(bid - 56320) * 256 + tid) * 4;
    const long NTXT = 768L * 2048;
    bf16x4 r;
    r[0] = r[1] = r[2] = r[3] = (bf16_t)0.f;
    if (t4 < NTXT) {
      const int row = (int)(t4 >> 11), col = (int)(t4 & 2047);
      if (row < 640) {
        const int b = row / 80, j = row - b * 80;
        if (j < TXT_) {
          const float4 v = *(const float4*)(enc + (((long)(b * 81 + j)) << 11) + col);
          r[0] = (bf16_t)v.x; r[1] = (bf16_t)v.y; r[2] = (bf16_t)v.z; r[3] = (bf16_t)v.w;
        }
      }
      *(bf16x4*)(a_txt + t4) = r;
    } else {
      const long u = t4 - NTXT;
      const int row = (int)(u >> 11), col = (int)(u & 2047);
      if (row < 32) {                      // ONLY B*NT=32 valid ip rows
        const int b = row >> 2, j = row & 3;
        const float4 v = *(const float4*)(enc + (((long)(b * 81 + TXT_ + j)) << 11) + col);
        r[0] = (bf16_t)v.x; r[1] = (bf16_t)v.y; r[2] = (bf16_t)v.z; r[3] = (bf16_t)v.w;
      }
      *(bf16x4*)(a_ip + u) = r;
    }
  }
}

// ---------------------------------------------------------------------------
extern "C" void kernel_launch(void* const* d_in, const int* in_sizes, int n_in,
                              void* d_out, int out_size, void* d_ws, size_t ws_size,
                              hipStream_t stream)
{
  (void)in_sizes; (void)n_in; (void)out_size; (void)ws_size;
  const float* hs  = (const float*)d_in[0];
  const float* enc = (const float*)d_in[1];
  const float* Wq  = (const float*)d_in[2];
  const float* Wk  = (const float*)d_in[3];
  const float* Wv  = (const float*)d_in[4];
  const float* Wki = (const float*)d_in[5];
  const float* Wvi = (const float*)d_in[6];
  const float* Wo  = (const float*)d_in[7];
  const float* bo  = (const float*)d_in[8];

  char* ws = (char*)d_ws;
  size_t off = 0;
  auto alloc = [&](size_t bytes) {
    char* p = ws + off;
    off += (bytes + 255) & ~(size_t)255;
    return p;
  };
  bf16_t* buf1   = (bf16_t*)alloc(83886080);  // hs_bf16 (A of GEMM1 + residual of GEMM2)
  bf16_t* qb     = (bf16_t*)alloc(83886080);  // Q (32768 x 1280), attn in-place
  bf16_t* Wq_t   = (bf16_t*)alloc(3276800);
  bf16_t* Wo_t   = (bf16_t*)alloc(3276800);
  bf16_t* Wkv_t  = (bf16_t*)alloc(10485760);
  bf16_t* Wip_t  = (bf16_t*)alloc(10485760);
  bf16_t* a_txt  = (bf16_t*)alloc(3145728);   // 768 x 2048 (padded)
  bf16_t* a_ip   = (bf16_t*)alloc(1048576);   // 256 x 2048 (padded)
  bf16_t* kv_txt = (bf16_t*)alloc(3932160);   // 768 x 2560
  bf16_t* kv_ip  = (bf16_t*)alloc(1310720);   // 256 x 2560

  // one merged preprocessing dispatch
  prep<<<58368, 256, 0, stream>>>(hs, buf1, Wq, Wo, Wk, Wv, Wki, Wvi,
                                  Wq_t, Wo_t, Wkv_t, Wip_t, enc, a_txt, a_ip);

  // GEMM1 + K|V + Kip|Vip in one dispatch (680 blocks)
  gemm1_fused<<<680, 512, 0, stream>>>(buf1, Wq_t, qb,
                                       a_txt, Wkv_t, kv_txt,
                                       a_ip, Wip_t, kv_ip);

  // fused dual-softmax attention, in-place on qb
  attn_fused<<<dim3(16, 20, 8), 256, 0, stream>>>(qb, kv_txt, kv_ip, qb);

  // out = attn @ Wo + bo + residual(bf16)
  gemm2<<<640, 512, 0, stream>>>(qb, Wo_t, (float*)d_out, bo, buf1);
}

// Round 16
// 441.825 us; speedup vs baseline: 1.2410x; 1.2410x over previous
//
#include <hip/hip_runtime.h>
#include <hip/hip_bf16.h>
#include <cstdint>
#include <cstddef>

// ---------------------------------------------------------------------------
// IPAttnProcessor: out = (softmax(QK^T)V + softmax(QKip^T)Vip) @ Wo + bo + residual
// B=8 SQ=4096 C=1280 CAD=2048 H=20 D=64 TXT=77 NT=4 IP_SCALE=1
// r16: r14 base (B back in LDS; r15's B-bypass falsified: scattered per-lane
// global B loads cost more than the LDS reads they saved). GEMM K-loop is the
// UNION of r5+r6: per-phase {barrier; lgkmcnt(0)+sched_barrier; prio; 16 MFMA;
// prio; barrier} lockstep AND ring-4 counted vmcnt(4) (never draining).
// This is the full m201 interlock; prior ports each lacked one half.
// ---------------------------------------------------------------------------

typedef __bf16 bf16_t;
typedef __bf16 bf16x8 __attribute__((ext_vector_type(8)));
typedef __bf16 bf16x4 __attribute__((ext_vector_type(4)));
typedef float  f32x4  __attribute__((ext_vector_type(4)));
typedef unsigned int u32x4 __attribute__((ext_vector_type(4)));

using as3_void  = __attribute__((address_space(3))) void;
using as1_cvoid = const __attribute__((address_space(1))) void;

#define TXT_ 77

__device__ __forceinline__ bf16x8 ld16(const void* p) {
  u32x4 v = *(const u32x4*)p;
  return __builtin_bit_cast(bf16x8, v);
}

// ---------------------------------------------------------------------------
// GEMM body: C[M,N] = A[M,K] @ Bt[N,K]^T. 256x256 tile, BK=32, 512 thr
// (8 waves = 2M x 4N, per-wave 128x64, acc[8][4]).
// LDS 128KB: A ring4 @0, B ring4 @64KB (r4-verified 0-conflict swizzle).
// K-tile t reads buf[t&3]; stages t+2 (slot's last reader >=2 tiles ago).
// Phase = { ds_reads | stage 1 half(t+2) | s_barrier | lgkmcnt(0)+sched_bar |
//           setprio(1) 16 MFMA setprio(0) | s_barrier }  x2 per tile.
// Tile-end vmcnt(4): retires exactly A(t+1)+B(t+1); A/B(t+2) stay in flight.
// Drain vmcnt(0) only at t==NTk-2.
// EPI=0: LDS-packed bf16 epilogue (512B full-line stores).
// EPI=2: f32 + bias[col] + bf16 residual.
// ---------------------------------------------------------------------------
template <int EPI>
__device__ __forceinline__ void gemm256_body(
    char* smem, const bf16_t* __restrict__ A, const bf16_t* __restrict__ Bt,
    void* __restrict__ Cout, int g, int ntn, int N, int K,
    const float* __restrict__ bias, const bf16_t* __restrict__ residual)
{
  const int tid = threadIdx.x, lane = tid & 63, wid = tid >> 6;
  const int wm = wid >> 2, wn = wid & 3;

  const long bm = (long)(g / ntn) * 256;
  const long bn = (long)(g % ntn) * 256;
  const int NTk = K >> 5;

  const int srow = lane >> 2;
  const int scol = ((lane & 3) ^ ((lane >> 3) & 3)) * 8;

  auto stageA = [&](int t) {
    const int buf = t & 3;
    const long k0 = (long)t << 5;
#pragma unroll
    for (int j = 0; j < 2; ++j) {
      const int ci = j * 8 + wid;
      const bf16_t* gp = A + (bm + ci * 16 + srow) * (long)K + k0 + scol;
      __builtin_amdgcn_global_load_lds((as1_cvoid*)gp,
          (as3_void*)(smem + buf * 16384 + ci * 1024), 16, 0, 0);
    }
  };
  auto stageB = [&](int t) {
    const int buf = t & 3;
    const long k0 = (long)t << 5;
#pragma unroll
    for (int j = 0; j < 2; ++j) {
      const int ci = j * 8 + wid;
      const bf16_t* gp = Bt + (bn + ci * 16 + srow) * (long)K + k0 + scol;
      __builtin_amdgcn_global_load_lds((as1_cvoid*)gp,
          (as3_void*)(smem + 65536 + buf * 16384 + ci * 1024), 16, 0, 0);
    }
  };

  const int l15 = lane & 15, kq = lane >> 4;
  const int rc16 = (kq ^ ((l15 >> 1) & 3)) << 4;

  f32x4 acc[8][4] = {};
  bf16x8 afr[4], bfr[4];

  stageA(0); stageB(0); stageA(1); stageB(1);
  asm volatile("s_waitcnt vmcnt(4)" ::: "memory");
  __builtin_amdgcn_s_barrier();

  for (int t = 0; t < NTk; ++t) {
    const char* sa = smem + (t & 3) * 16384;
    const char* sb = smem + 65536 + (t & 3) * 16384;
    const bool pf = (t + 2 < NTk);

    // ---- P0: ds_read B all + A m0-3 | stage A(t+2) | BAR | lgkm | MFMA | BAR
#pragma unroll
    for (int n = 0; n < 4; ++n)
      bfr[n] = ld16(sb + (wn * 64 + n * 16 + l15) * 64 + rc16);
#pragma unroll
    for (int m = 0; m < 4; ++m)
      afr[m] = ld16(sa + (wm * 128 + m * 16 + l15) * 64 + rc16);
    if (pf) stageA(t + 2);
    __builtin_amdgcn_s_barrier();
    asm volatile("s_waitcnt lgkmcnt(0)" ::: "memory");
    __builtin_amdgcn_sched_barrier(0);
    __builtin_amdgcn_s_setprio(1);
#pragma unroll
    for (int m = 0; m < 4; ++m)
#pragma unroll
      for (int n = 0; n < 4; ++n)
        acc[m][n] = __builtin_amdgcn_mfma_f32_16x16x32_bf16(afr[m], bfr[n], acc[m][n], 0, 0, 0);
    __builtin_amdgcn_s_setprio(0);
    __builtin_amdgcn_s_barrier();

    // ---- P1: ds_read A m4-7 | stage B(t+2) | BAR | lgkm | MFMA | vmcnt | BAR
#pragma unroll
    for (int m = 0; m < 4; ++m)
      afr[m] = ld16(sa + (wm * 128 + (m + 4) * 16 + l15) * 64 + rc16);
    if (pf) stageB(t + 2);
    __builtin_amdgcn_s_barrier();
    asm volatile("s_waitcnt lgkmcnt(0)" ::: "memory");
    __builtin_amdgcn_sched_barrier(0);
    __builtin_amdgcn_s_setprio(1);
#pragma unroll
    for (int m = 0; m < 4; ++m)
#pragma unroll
      for (int n = 0; n < 4; ++n)
        acc[m + 4][n] = __builtin_amdgcn_mfma_f32_16x16x32_bf16(afr[m], bfr[n], acc[m + 4][n], 0, 0, 0);
    __builtin_amdgcn_s_setprio(0);
    // tile-end: counted wait -- t+1 resident, t+2's 4 loads stay in flight
    if (t == NTk - 2) asm volatile("s_waitcnt vmcnt(0)" ::: "memory");
    else              asm volatile("s_waitcnt vmcnt(4)" ::: "memory");
    __builtin_amdgcn_s_barrier();
  }

  const int orow0 = (lane >> 4) << 2;
  if constexpr (EPI == 0) {
    // LDS-packed epilogue: acc -> smem bf16 [256][256], then 512B full-line sweeps
    bf16_t* cl = (bf16_t*)smem;
    const int lrow0 = wm * 128 + orow0;
    const int lcol0 = wn * 64 + l15;
#pragma unroll
    for (int m = 0; m < 8; ++m)
#pragma unroll
      for (int n = 0; n < 4; ++n)
#pragma unroll
        for (int r = 0; r < 4; ++r)
          cl[(lrow0 + m * 16 + r) * 256 + lcol0 + n * 16] = (bf16_t)acc[m][n][r];
    __syncthreads();
    const int rr = tid >> 5, cc = tid & 31;
#pragma unroll
    for (int s = 0; s < 16; ++s) {
      const int row = s * 16 + rr;
      const u32x4 v = *(const u32x4*)(cl + row * 256 + cc * 8);
      *(u32x4*)((bf16_t*)Cout + (bm + row) * (long)N + bn + cc * 8) = v;
    }
  } else {
#pragma unroll
    for (int m = 0; m < 8; ++m) {
#pragma unroll
      for (int n = 0; n < 4; ++n) {
        const long col = bn + wn * 64 + n * 16 + l15;
#pragma unroll
        for (int r = 0; r < 4; ++r) {
          const long row = bm + wm * 128 + m * 16 + orow0 + r;
          ((float*)Cout)[row * N + col] =
              acc[m][n][r] + bias[col] + (float)residual[row * N + col];
        }
      }
    }
  }
}

// GEMM1 + projections fused in one dispatch (680 blocks):
//   0-639:   Q = hs_bf16 @ Wq    (XCD-chunked swizzle over 640)
//   640-669: K|V = a_txt(768 pad) @ [Wk|Wv]   (3x10 tiles, K=2048)
//   670-679: Kip|Vip = a_ip(256 pad) @ [Wk_ip|Wv_ip] (1x10 tiles)
__global__ __launch_bounds__(512, 2)
void gemm1_fused(const bf16_t* __restrict__ hsb, const bf16_t* __restrict__ Wq_t,
                 bf16_t* __restrict__ qb,
                 const bf16_t* __restrict__ a_txt, const bf16_t* __restrict__ Wkv_t,
                 bf16_t* __restrict__ kv_txt,
                 const bf16_t* __restrict__ a_ip, const bf16_t* __restrict__ Wip_t,
                 bf16_t* __restrict__ kv_ip)
{
  __shared__ __align__(16) char smem[131072];
  const int bid = blockIdx.x;
  const bf16_t *A, *Bt;
  bf16_t* C;
  int g, ntn, N, K;
  if (bid < 640) {
    g = (bid & 7) * 80 + (bid >> 3);   // bijective on [0,640)
    A = hsb; Bt = Wq_t; C = qb; ntn = 5; N = 1280; K = 1280;
  } else if (bid < 670) {
    g = bid - 640; A = a_txt; Bt = Wkv_t; C = kv_txt; ntn = 10; N = 2560; K = 2048;
  } else {
    g = bid - 670; A = a_ip; Bt = Wip_t; C = kv_ip; ntn = 10; N = 2560; K = 2048;
  }
  gemm256_body<0>(smem, A, Bt, C, g, ntn, N, K, nullptr, nullptr);
}

// GEMM2: out = attn @ Wo + bo + residual(bf16), 640 blocks, XCD swizzle.
__global__ __launch_bounds__(512, 2)
void gemm2(const bf16_t* __restrict__ A, const bf16_t* __restrict__ Bt,
           float* __restrict__ Cout, const float* __restrict__ bias,
           const bf16_t* __restrict__ residual)
{
  __shared__ __align__(16) char smem[131072];
  const int bid = blockIdx.x;
  const int g = (bid & 7) * 80 + (bid >> 3);
  gemm256_body<2>(smem, A, Bt, Cout, g, 5, 1280, 1280, bias, residual);
}

// ---------------------------------------------------------------------------
// Fused attention (r8-unchanged; writes in-place over Q).
// ---------------------------------------------------------------------------
__global__ __launch_bounds__(256, 3)
void attn_fused(const bf16_t* __restrict__ q, const bf16_t* __restrict__ kvt,
                const bf16_t* __restrict__ kvip, bf16_t* __restrict__ outp)
{
  __shared__ __align__(16) bf16_t K_lds[80 * 64];
  __shared__ __align__(16) bf16_t Kip_lds[16 * 64];
  __shared__ __align__(16) bf16_t Vt_lds[64 * 128];
  __shared__ __align__(16) bf16_t P_lds[4][16 * 128];

  const int tid = threadIdx.x, lane = tid & 63, wid = tid >> 6;
  const int h = blockIdx.y, b = blockIdx.z;
  const int kvcol = h << 6;

  for (int idx = tid; idx < 640; idx += 256) {
    const int j = idx >> 3, c = idx & 7;
    bf16x8 v = {};
    if (j < TXT_) v = ld16(kvt + (long)(b * 80 + j) * 2560 + kvcol + c * 8);
    *(bf16x8*)((char*)K_lds + j * 128 + ((c ^ (j & 7)) << 4)) = v;
  }
  if (tid < 128) {
    const int j = tid >> 3, c = tid & 7;
    bf16x8 v = {};
    if (j < 4) v = ld16(kvip + (long)(b * 4 + j) * 2560 + kvcol + c * 8);
    *(bf16x8*)((char*)Kip_lds + j * 128 + ((c ^ (j & 7)) << 4)) = v;
  }
  for (int idx = tid; idx < 1024; idx += 256) {
    const int key = idx >> 3, c = idx & 7;
    bf16x8 v = {};
    if (key < TXT_)
      v = ld16(kvt + (long)(b * 80 + key) * 2560 + 1280 + kvcol + c * 8);
    else if (key >= 96 && key < 100)
      v = ld16(kvip + (long)(b * 4 + key - 96) * 2560 + 1280 + kvcol + c * 8);
#pragma unroll
    for (int e = 0; e < 8; ++e) {
      const int d = c * 8 + e;
      *(bf16_t*)((char*)Vt_lds + d * 256 + ((key * 2) ^ ((d & 7) << 4))) = v[e];
    }
  }
  for (int idx = tid; idx < 1024; idx += 256)
    *(bf16x8*)((char*)P_lds + idx * 16) = (bf16x8){};
  __syncthreads();

  const int l15 = lane & 15, hi = lane >> 4;
  const int dblk = hi << 3;
  const int prow0 = hi << 2;
  const float scale = 0.125f;
  char* const pw = (char*)P_lds[wid];

  const long qrow0 = (long)b * 4096 + ((long)blockIdx.x << 8) + (wid << 6);
  bf16x8 qf[4][2];
#pragma unroll
  for (int ms = 0; ms < 4; ++ms) {
    const bf16_t* qp = q + (qrow0 + ms * 16 + l15) * 1280 + kvcol;
    qf[ms][0] = ld16(qp + dblk);
    qf[ms][1] = ld16(qp + 32 + dblk);
  }

#pragma unroll
  for (int ms = 0; ms < 4; ++ms) {
    f32x4 sc[5];
#pragma unroll
    for (int t = 0; t < 5; ++t) {
      const int j = (t << 4) + l15;
      const bf16x8 k0 = ld16((char*)K_lds + j * 128 + ((hi ^ (j & 7)) << 4));
      const bf16x8 k1 = ld16((char*)K_lds + j * 128 + (((4 + hi) ^ (j & 7)) << 4));
      f32x4 z = {0.f, 0.f, 0.f, 0.f};
      z = __builtin_amdgcn_mfma_f32_16x16x32_bf16(qf[ms][0], k0, z, 0, 0, 0);
      z = __builtin_amdgcn_mfma_f32_16x16x32_bf16(qf[ms][1], k1, z, 0, 0, 0);
      sc[t] = z;
    }
#pragma unroll
    for (int t = 0; t < 5; ++t) {
      const bool valid = ((t << 4) + l15) < TXT_;
#pragma unroll
      for (int r = 0; r < 4; ++r)
        sc[t][r] = valid ? sc[t][r] * scale : -1e30f;
    }

#pragma unroll
    for (int r = 0; r < 4; ++r) {
      float m = sc[0][r];
#pragma unroll
      for (int t = 1; t < 5; ++t) m = fmaxf(m, sc[t][r]);
      m = fmaxf(m, __shfl_xor(m, 1));
      m = fmaxf(m, __shfl_xor(m, 2));
      m = fmaxf(m, __shfl_xor(m, 4));
      m = fmaxf(m, __shfl_xor(m, 8));
      float l = 0.f;
#pragma unroll
      for (int t = 0; t < 5; ++t) { const float p = __expf(sc[t][r] - m); sc[t][r] = p; l += p; }
      l += __shfl_xor(l, 1);
      l += __shfl_xor(l, 2);
      l += __shfl_xor(l, 4);
      l += __shfl_xor(l, 8);
      const float inv = 1.f / l;
      const int row = prow0 + r;
#pragma unroll
      for (int t = 0; t < 5; ++t)
        *(bf16_t*)(pw + row * 256 + ((((t << 4) + l15) * 2) ^ ((row & 7) << 4))) =
            (bf16_t)(sc[t][r] * inv);
    }

    {
      const bf16x8 ki0 = ld16((char*)Kip_lds + l15 * 128 + ((hi ^ (l15 & 7)) << 4));
      const bf16x8 ki1 = ld16((char*)Kip_lds + l15 * 128 + (((4 + hi) ^ (l15 & 7)) << 4));
      f32x4 z = {0.f, 0.f, 0.f, 0.f};
      z = __builtin_amdgcn_mfma_f32_16x16x32_bf16(qf[ms][0], ki0, z, 0, 0, 0);
      z = __builtin_amdgcn_mfma_f32_16x16x32_bf16(qf[ms][1], ki1, z, 0, 0, 0);
      const bool vip = l15 < 4;
#pragma unroll
      for (int r = 0; r < 4; ++r) {
        const float s = vip ? z[r] * scale : -1e30f;
        float m = s;
        m = fmaxf(m, __shfl_xor(m, 1));
        m = fmaxf(m, __shfl_xor(m, 2));
        m = fmaxf(m, __shfl_xor(m, 4));
        m = fmaxf(m, __shfl_xor(m, 8));
        const float p = __expf(s - m);
        float l = p;
        l += __shfl_xor(l, 1);
        l += __shfl_xor(l, 2);
        l += __shfl_xor(l, 4);
        l += __shfl_xor(l, 8);
        const int row = prow0 + r;
        *(bf16_t*)(pw + row * 256 + (((96 + l15) * 2) ^ ((row & 7) << 4))) =
            (bf16_t)(p * (1.f / l));
      }
    }

    f32x4 o[4] = {};
#pragma unroll
    for (int s = 0; s < 4; ++s) {
      const bf16x8 pa =
          ld16(pw + l15 * 256 + ((((s << 2) + hi) << 4) ^ ((l15 & 7) << 4)));
#pragma unroll
      for (int n = 0; n < 4; ++n) {
        const int d = (n << 4) + l15;
        const bf16x8 vb =
            ld16((char*)Vt_lds + d * 256 + ((((s << 2) + hi) << 4) ^ ((d & 7) << 4)));
        o[n] = __builtin_amdgcn_mfma_f32_16x16x32_bf16(pa, vb, o[n], 0, 0, 0);
      }
    }

    const long orow = qrow0 + ms * 16 + prow0;
#pragma unroll
    for (int n = 0; n < 4; ++n)
#pragma unroll
      for (int r = 0; r < 4; ++r)
        outp[(orow + r) * 1280 + kvcol + (n << 4) + l15] = (bf16_t)o[n][r];
  }
}

// ---------------------------------------------------------------------------
// prep: merged cvt_bf16 (blocks 0-40959) + weight transpose (40960-56319)
// + pack_enc with padding (56320-58367). Valid ip rows: 32 (=B*NT).
// ---------------------------------------------------------------------------
__global__ __launch_bounds__(256)
void prep(const float* __restrict__ hs, bf16_t* __restrict__ hsb,
          const float* __restrict__ Wq, const float* __restrict__ Wo,
          const float* __restrict__ Wk, const float* __restrict__ Wv,
          const float* __restrict__ Wki, const float* __restrict__ Wvi,
          bf16_t* __restrict__ Wq_t, bf16_t* __restrict__ Wo_t,
          bf16_t* __restrict__ Wkv_t, bf16_t* __restrict__ Wip_t,
          const float* __restrict__ enc, bf16_t* __restrict__ a_txt,
          bf16_t* __restrict__ a_ip)
{
  __shared__ float tile[32][33];
  const int bid = blockIdx.x, tid = threadIdx.x;

  if (bid < 40960) {                       // hs fp32 -> bf16 (41943040 elems)
    const long i = ((long)bid * 256 + tid) * 4;
    const float4 v = *(const float4*)(hs + i);
    bf16x4 r;
    r[0] = (bf16_t)v.x; r[1] = (bf16_t)v.y; r[2] = (bf16_t)v.z; r[3] = (bf16_t)v.w;
    *(bf16x4*)(hsb + i) = r;
  } else if (bid < 56320) {                // weight transpose+cvt (6 weights)
    const int idx = bid - 40960;
    const int z = idx / 2560, rem = idx % 2560;
    const int kx = rem & 63, ny = rem >> 6; // 64 k-tiles x 40 n-tiles
    const float* in;
    bf16_t* out;
    int K;
    switch (z) {
      case 0:  in = Wq;  out = Wq_t;                      K = 1280; break;
      case 1:  in = Wo;  out = Wo_t;                      K = 1280; break;
      case 2:  in = Wk;  out = Wkv_t;                     K = 2048; break;
      case 3:  in = Wv;  out = Wkv_t + (long)1280 * 2048; K = 2048; break;
      case 4:  in = Wki; out = Wip_t;                     K = 2048; break;
      default: in = Wvi; out = Wip_t + (long)1280 * 2048; K = 2048; break;
    }
    const int k0 = kx * 32, n0 = ny * 32;
    if (k0 < K) {
      const int tx = tid & 31, ty = tid >> 5;
      for (int i = ty; i < 32; i += 8)
        tile[i][tx] = in[(long)(k0 + i) * 1280 + n0 + tx];
      __syncthreads();
      for (int i = ty; i < 32; i += 8)
        out[(long)(n0 + i) * K + k0 + tx] = (bf16_t)tile[tx][i];
    }
  } else {                                 // encoder pack + zero-pad
    const long t4 = ((long)(bid - 56320) * 256 + tid) * 4;
    const long NTXT = 768L * 2048;
    bf16x4 r;
    r[0] = r[1] = r[2] = r[3] = (bf16_t)0.f;
    if (t4 < NTXT) {
      const int row = (int)(t4 >> 11), col = (int)(t4 & 2047);
      if (row < 640) {
        const int b = row / 80, j = row - b * 80;
        if (j < TXT_) {
          const float4 v = *(const float4*)(enc + (((long)(b * 81 + j)) << 11) + col);
          r[0] = (bf16_t)v.x; r[1] = (bf16_t)v.y; r[2] = (bf16_t)v.z; r[3] = (bf16_t)v.w;
        }
      }
      *(bf16x4*)(a_txt + t4) = r;
    } else {
      const long u = t4 - NTXT;
      const int row = (int)(u >> 11), col = (int)(u & 2047);
      if (row < 32) {                      // ONLY B*NT=32 valid ip rows
        const int b = row >> 2, j = row & 3;
        const float4 v = *(const float4*)(enc + (((long)(b * 81 + TXT_ + j)) << 11) + col);
        r[0] = (bf16_t)v.x; r[1] = (bf16_t)v.y; r[2] = (bf16_t)v.z; r[3] = (bf16_t)v.w;
      }
      *(bf16x4*)(a_ip + u) = r;
    }
  }
}

// ---------------------------------------------------------------------------
extern "C" void kernel_launch(void* const* d_in, const int* in_sizes, int n_in,
                              void* d_out, int out_size, void* d_ws, size_t ws_size,
                              hipStream_t stream)
{
  (void)in_sizes; (void)n_in; (void)out_size; (void)ws_size;
  const float* hs  = (const float*)d_in[0];
  const float* enc = (const float*)d_in[1];
  const float* Wq  = (const float*)d_in[2];
  const float* Wk  = (const float*)d_in[3];
  const float* Wv  = (const float*)d_in[4];
  const float* Wki = (const float*)d_in[5];
  const float* Wvi = (const float*)d_in[6];
  const float* Wo  = (const float*)d_in[7];
  const float* bo  = (const float*)d_in[8];

  char* ws = (char*)d_ws;
  size_t off = 0;
  auto alloc = [&](size_t bytes) {
    char* p = ws + off;
    off += (bytes + 255) & ~(size_t)255;
    return p;
  };
  bf16_t* buf1   = (bf16_t*)alloc(83886080);  // hs_bf16 (A of GEMM1 + residual of GEMM2)
  bf16_t* qb     = (bf16_t*)alloc(83886080);  // Q (32768 x 1280), attn in-place
  bf16_t* Wq_t   = (bf16_t*)alloc(3276800);
  bf16_t* Wo_t   = (bf16_t*)alloc(3276800);
  bf16_t* Wkv_t  = (bf16_t*)alloc(10485760);
  bf16_t* Wip_t  = (bf16_t*)alloc(10485760);
  bf16_t* a_txt  = (bf16_t*)alloc(3145728);   // 768 x 2048 (padded)
  bf16_t* a_ip   = (bf16_t*)alloc(1048576);   // 256 x 2048 (padded)
  bf16_t* kv_txt = (bf16_t*)alloc(3932160);   // 768 x 2560
  bf16_t* kv_ip  = (bf16_t*)alloc(1310720);   // 256 x 2560

  // one merged preprocessing dispatch
  prep<<<58368, 256, 0, stream>>>(hs, buf1, Wq, Wo, Wk, Wv, Wki, Wvi,
                                  Wq_t, Wo_t, Wkv_t, Wip_t, enc, a_txt, a_ip);

  // GEMM1 + K|V + Kip|Vip in one dispatch (680 blocks)
  gemm1_fused<<<680, 512, 0, stream>>>(buf1, Wq_t, qb,
                                       a_txt, Wkv_t, kv_txt,
                                       a_ip, Wip_t, kv_ip);

  // fused dual-softmax attention, in-place on qb
  attn_fused<<<dim3(16, 20, 8), 256, 0, stream>>>(qb, kv_txt, kv_ip, qb);

  // out = attn @ Wo + bo + residual(bf16)
  gemm2<<<640, 512, 0, stream>>>(qb, Wo_t, (float*)d_out, bo, buf1);
}

// Round 17
// 424.310 us; speedup vs baseline: 1.2922x; 1.0413x over previous
//
#include <hip/hip_runtime.h>
#include <hip/hip_bf16.h>
#include <cstdint>
#include <cstddef>

// ---------------------------------------------------------------------------
// IPAttnProcessor: out = (softmax(QK^T)V + softmax(QKip^T)Vip) @ Wo + bo + residual
// B=8 SQ=4096 C=1280 CAD=2048 H=20 D=64 TXT=77 NT=4 IP_SCALE=1
// FINAL (r17 = r14 verbatim, best measured 419us): GEMM core = r8 config
// (256^2 tile, BK=32, ring-4 LDS 128KB, counted vmcnt(4), 16x16 MFMA,
// verified 0-conflict swizzle, LDS-packed bf16 epilogue). Projections merged
// into GEMM1's dispatch tail; cvt/transpose/pack in one prep kernel.
// Ceiling note: 7 K-loop schedules (2-phase/4-phase/8-phase-union, 32x32
// MFMA, B-bypass, occupancy 2/CU) all land at 160-175us / 25-28% MfmaUtil
// -> structure ceiling for K=N=1280 at 1 block/CU, not a schedule artifact.
// ---------------------------------------------------------------------------

typedef __bf16 bf16_t;
typedef __bf16 bf16x8 __attribute__((ext_vector_type(8)));
typedef __bf16 bf16x4 __attribute__((ext_vector_type(4)));
typedef float  f32x4  __attribute__((ext_vector_type(4)));
typedef unsigned int u32x4 __attribute__((ext_vector_type(4)));

using as3_void  = __attribute__((address_space(3))) void;
using as1_cvoid = const __attribute__((address_space(1))) void;

#define TXT_ 77

__device__ __forceinline__ bf16x8 ld16(const void* p) {
  u32x4 v = *(const u32x4*)p;
  return __builtin_bit_cast(bf16x8, v);
}

// ---------------------------------------------------------------------------
// r8-exact GEMM body: C[M,N] = A[M,K] @ Bt[N,K]^T. 256x256 tile, BK=32,
// 512 thr (8 waves = 2M x 4N, per-wave 128x64, acc[8][4]).
// LDS 128KB: A ring4 @0, B ring4 @64KB. K-tile t reads buf[t&3], stages t+2
// (race-free); tile-end s_waitcnt vmcnt(4) counted, drain at NTk-2.
// EPI=0: LDS-packed bf16 epilogue (512B full-line stores).
// EPI=2: f32 + bias[col] + bf16 residual (64B stores).
// ---------------------------------------------------------------------------
template <int EPI>
__device__ __forceinline__ void gemm256_body(
    char* smem, const bf16_t* __restrict__ A, const bf16_t* __restrict__ Bt,
    void* __restrict__ Cout, int g, int ntn, int N, int K,
    const float* __restrict__ bias, const bf16_t* __restrict__ residual)
{
  const int tid = threadIdx.x, lane = tid & 63, wid = tid >> 6;
  const int wm = wid >> 2, wn = wid & 3;

  const long bm = (long)(g / ntn) * 256;
  const long bn = (long)(g % ntn) * 256;
  const int NTk = K >> 5;

  const int srow = lane >> 2;
  const int scol = ((lane & 3) ^ ((lane >> 3) & 3)) * 8;

  auto stageA = [&](int t) {
    const int buf = t & 3;
    const long k0 = (long)t << 5;
#pragma unroll
    for (int j = 0; j < 2; ++j) {
      const int ci = j * 8 + wid;
      const bf16_t* gp = A + (bm + ci * 16 + srow) * (long)K + k0 + scol;
      __builtin_amdgcn_global_load_lds((as1_cvoid*)gp,
          (as3_void*)(smem + buf * 16384 + ci * 1024), 16, 0, 0);
    }
  };
  auto stageB = [&](int t) {
    const int buf = t & 3;
    const long k0 = (long)t << 5;
#pragma unroll
    for (int j = 0; j < 2; ++j) {
      const int ci = j * 8 + wid;
      const bf16_t* gp = Bt + (bn + ci * 16 + srow) * (long)K + k0 + scol;
      __builtin_amdgcn_global_load_lds((as1_cvoid*)gp,
          (as3_void*)(smem + 65536 + buf * 16384 + ci * 1024), 16, 0, 0);
    }
  };

  const int l15 = lane & 15, kq = lane >> 4;
  const int rc16 = (kq ^ ((l15 >> 1) & 3)) << 4;

  f32x4 acc[8][4] = {};
  bf16x8 afr[4], bfr[4];

  stageA(0); stageB(0); stageA(1); stageB(1);
  asm volatile("s_waitcnt vmcnt(4)" ::: "memory");
  __builtin_amdgcn_s_barrier();

  for (int t = 0; t < NTk; ++t) {
    const char* sa = smem + (t & 3) * 16384;
    const char* sb = smem + 65536 + (t & 3) * 16384;
    const bool pf = (t + 2 < NTk);

    // ---- P0: B all + A m0-3, stage A(t+2), MFMA upper half ----
#pragma unroll
    for (int n = 0; n < 4; ++n)
      bfr[n] = ld16(sb + (wn * 64 + n * 16 + l15) * 64 + rc16);
#pragma unroll
    for (int m = 0; m < 4; ++m)
      afr[m] = ld16(sa + (wm * 128 + m * 16 + l15) * 64 + rc16);
    if (pf) stageA(t + 2);
    __builtin_amdgcn_s_setprio(1);
#pragma unroll
    for (int m = 0; m < 4; ++m)
#pragma unroll
      for (int n = 0; n < 4; ++n)
        acc[m][n] = __builtin_amdgcn_mfma_f32_16x16x32_bf16(afr[m], bfr[n], acc[m][n], 0, 0, 0);
    __builtin_amdgcn_s_setprio(0);

    // ---- P1: A m4-7, stage B(t+2), MFMA lower half ----
#pragma unroll
    for (int m = 0; m < 4; ++m)
      afr[m] = ld16(sa + (wm * 128 + (m + 4) * 16 + l15) * 64 + rc16);
    if (pf) stageB(t + 2);
    __builtin_amdgcn_s_setprio(1);
#pragma unroll
    for (int m = 0; m < 4; ++m)
#pragma unroll
      for (int n = 0; n < 4; ++n)
        acc[m + 4][n] = __builtin_amdgcn_mfma_f32_16x16x32_bf16(afr[m], bfr[n], acc[m + 4][n], 0, 0, 0);
    __builtin_amdgcn_s_setprio(0);

    // ---- tile-end: counted wait ----
    if (t == NTk - 2) asm volatile("s_waitcnt vmcnt(0)" ::: "memory");
    else              asm volatile("s_waitcnt vmcnt(4)" ::: "memory");
    __builtin_amdgcn_s_barrier();
  }

  const int orow0 = (lane >> 4) << 2;
  if constexpr (EPI == 0) {
    // LDS-packed epilogue: acc -> smem bf16 [256][256], then 512B full-line sweeps
    bf16_t* cl = (bf16_t*)smem;
    const int lrow0 = wm * 128 + orow0;
    const int lcol0 = wn * 64 + l15;
#pragma unroll
    for (int m = 0; m < 8; ++m)
#pragma unroll
      for (int n = 0; n < 4; ++n)
#pragma unroll
        for (int r = 0; r < 4; ++r)
          cl[(lrow0 + m * 16 + r) * 256 + lcol0 + n * 16] = (bf16_t)acc[m][n][r];
    __syncthreads();
    const int rr = tid >> 5, cc = tid & 31;
#pragma unroll
    for (int s = 0; s < 16; ++s) {
      const int row = s * 16 + rr;
      const u32x4 v = *(const u32x4*)(cl + row * 256 + cc * 8);
      *(u32x4*)((bf16_t*)Cout + (bm + row) * (long)N + bn + cc * 8) = v;
    }
  } else {
#pragma unroll
    for (int m = 0; m < 8; ++m) {
#pragma unroll
      for (int n = 0; n < 4; ++n) {
        const long col = bn + wn * 64 + n * 16 + l15;
#pragma unroll
        for (int r = 0; r < 4; ++r) {
          const long row = bm + wm * 128 + m * 16 + orow0 + r;
          ((float*)Cout)[row * N + col] =
              acc[m][n][r] + bias[col] + (float)residual[row * N + col];
        }
      }
    }
  }
}

// GEMM1 + projections fused in one dispatch (680 blocks):
//   0-639:   Q = hs_bf16 @ Wq    (XCD-chunked swizzle over 640)
//   640-669: K|V = a_txt(768 pad) @ [Wk|Wv]   (3x10 tiles, K=2048)
//   670-679: Kip|Vip = a_ip(256 pad) @ [Wk_ip|Wv_ip] (1x10 tiles)
__global__ __launch_bounds__(512, 2)
void gemm1_fused(const bf16_t* __restrict__ hsb, const bf16_t* __restrict__ Wq_t,
                 bf16_t* __restrict__ qb,
                 const bf16_t* __restrict__ a_txt, const bf16_t* __restrict__ Wkv_t,
                 bf16_t* __restrict__ kv_txt,
                 const bf16_t* __restrict__ a_ip, const bf16_t* __restrict__ Wip_t,
                 bf16_t* __restrict__ kv_ip)
{
  __shared__ __align__(16) char smem[131072];
  const int bid = blockIdx.x;
  const bf16_t *A, *Bt;
  bf16_t* C;
  int g, ntn, N, K;
  if (bid < 640) {
    g = (bid & 7) * 80 + (bid >> 3);   // bijective on [0,640)
    A = hsb; Bt = Wq_t; C = qb; ntn = 5; N = 1280; K = 1280;
  } else if (bid < 670) {
    g = bid - 640; A = a_txt; Bt = Wkv_t; C = kv_txt; ntn = 10; N = 2560; K = 2048;
  } else {
    g = bid - 670; A = a_ip; Bt = Wip_t; C = kv_ip; ntn = 10; N = 2560; K = 2048;
  }
  gemm256_body<0>(smem, A, Bt, C, g, ntn, N, K, nullptr, nullptr);
}

// GEMM2: out = attn @ Wo + bo + residual(bf16), 640 blocks, XCD swizzle.
__global__ __launch_bounds__(512, 2)
void gemm2(const bf16_t* __restrict__ A, const bf16_t* __restrict__ Bt,
           float* __restrict__ Cout, const float* __restrict__ bias,
           const bf16_t* __restrict__ residual)
{
  __shared__ __align__(16) char smem[131072];
  const int bid = blockIdx.x;
  const int g = (bid & 7) * 80 + (bid >> 3);
  gemm256_body<2>(smem, A, Bt, Cout, g, 5, 1280, 1280, bias, residual);
}

// ---------------------------------------------------------------------------
// Fused attention (r8-unchanged; writes in-place over Q).
// ---------------------------------------------------------------------------
__global__ __launch_bounds__(256, 3)
void attn_fused(const bf16_t* __restrict__ q, const bf16_t* __restrict__ kvt,
                const bf16_t* __restrict__ kvip, bf16_t* __restrict__ outp)
{
  __shared__ __align__(16) bf16_t K_lds[80 * 64];
  __shared__ __align__(16) bf16_t Kip_lds[16 * 64];
  __shared__ __align__(16) bf16_t Vt_lds[64 * 128];
  __shared__ __align__(16) bf16_t P_lds[4][16 * 128];

  const int tid = threadIdx.x, lane = tid & 63, wid = tid >> 6;
  const int h = blockIdx.y, b = blockIdx.z;
  const int kvcol = h << 6;

  for (int idx = tid; idx < 640; idx += 256) {
    const int j = idx >> 3, c = idx & 7;
    bf16x8 v = {};
    if (j < TXT_) v = ld16(kvt + (long)(b * 80 + j) * 2560 + kvcol + c * 8);
    *(bf16x8*)((char*)K_lds + j * 128 + ((c ^ (j & 7)) << 4)) = v;
  }
  if (tid < 128) {
    const int j = tid >> 3, c = tid & 7;
    bf16x8 v = {};
    if (j < 4) v = ld16(kvip + (long)(b * 4 + j) * 2560 + kvcol + c * 8);
    *(bf16x8*)((char*)Kip_lds + j * 128 + ((c ^ (j & 7)) << 4)) = v;
  }
  for (int idx = tid; idx < 1024; idx += 256) {
    const int key = idx >> 3, c = idx & 7;
    bf16x8 v = {};
    if (key < TXT_)
      v = ld16(kvt + (long)(b * 80 + key) * 2560 + 1280 + kvcol + c * 8);
    else if (key >= 96 && key < 100)
      v = ld16(kvip + (long)(b * 4 + key - 96) * 2560 + 1280 + kvcol + c * 8);
#pragma unroll
    for (int e = 0; e < 8; ++e) {
      const int d = c * 8 + e;
      *(bf16_t*)((char*)Vt_lds + d * 256 + ((key * 2) ^ ((d & 7) << 4))) = v[e];
    }
  }
  for (int idx = tid; idx < 1024; idx += 256)
    *(bf16x8*)((char*)P_lds + idx * 16) = (bf16x8){};
  __syncthreads();

  const int l15 = lane & 15, hi = lane >> 4;
  const int dblk = hi << 3;
  const int prow0 = hi << 2;
  const float scale = 0.125f;
  char* const pw = (char*)P_lds[wid];

  const long qrow0 = (long)b * 4096 + ((long)blockIdx.x << 8) + (wid << 6);
  bf16x8 qf[4][2];
#pragma unroll
  for (int ms = 0; ms < 4; ++ms) {
    const bf16_t* qp = q + (qrow0 + ms * 16 + l15) * 1280 + kvcol;
    qf[ms][0] = ld16(qp + dblk);
    qf[ms][1] = ld16(qp + 32 + dblk);
  }

#pragma unroll
  for (int ms = 0; ms < 4; ++ms) {
    f32x4 sc[5];
#pragma unroll
    for (int t = 0; t < 5; ++t) {
      const int j = (t << 4) + l15;
      const bf16x8 k0 = ld16((char*)K_lds + j * 128 + ((hi ^ (j & 7)) << 4));
      const bf16x8 k1 = ld16((char*)K_lds + j * 128 + (((4 + hi) ^ (j & 7)) << 4));
      f32x4 z = {0.f, 0.f, 0.f, 0.f};
      z = __builtin_amdgcn_mfma_f32_16x16x32_bf16(qf[ms][0], k0, z, 0, 0, 0);
      z = __builtin_amdgcn_mfma_f32_16x16x32_bf16(qf[ms][1], k1, z, 0, 0, 0);
      sc[t] = z;
    }
#pragma unroll
    for (int t = 0; t < 5; ++t) {
      const bool valid = ((t << 4) + l15) < TXT_;
#pragma unroll
      for (int r = 0; r < 4; ++r)
        sc[t][r] = valid ? sc[t][r] * scale : -1e30f;
    }

#pragma unroll
    for (int r = 0; r < 4; ++r) {
      float m = sc[0][r];
#pragma unroll
      for (int t = 1; t < 5; ++t) m = fmaxf(m, sc[t][r]);
      m = fmaxf(m, __shfl_xor(m, 1));
      m = fmaxf(m, __shfl_xor(m, 2));
      m = fmaxf(m, __shfl_xor(m, 4));
      m = fmaxf(m, __shfl_xor(m, 8));
      float l = 0.f;
#pragma unroll
      for (int t = 0; t < 5; ++t) { const float p = __expf(sc[t][r] - m); sc[t][r] = p; l += p; }
      l += __shfl_xor(l, 1);
      l += __shfl_xor(l, 2);
      l += __shfl_xor(l, 4);
      l += __shfl_xor(l, 8);
      const float inv = 1.f / l;
      const int row = prow0 + r;
#pragma unroll
      for (int t = 0; t < 5; ++t)
        *(bf16_t*)(pw + row * 256 + ((((t << 4) + l15) * 2) ^ ((row & 7) << 4))) =
            (bf16_t)(sc[t][r] * inv);
    }

    {
      const bf16x8 ki0 = ld16((char*)Kip_lds + l15 * 128 + ((hi ^ (l15 & 7)) << 4));
      const bf16x8 ki1 = ld16((char*)Kip_lds + l15 * 128 + (((4 + hi) ^ (l15 & 7)) << 4));
      f32x4 z = {0.f, 0.f, 0.f, 0.f};
      z = __builtin_amdgcn_mfma_f32_16x16x32_bf16(qf[ms][0], ki0, z, 0, 0, 0);
      z = __builtin_amdgcn_mfma_f32_16x16x32_bf16(qf[ms][1], ki1, z, 0, 0, 0);
      const bool vip = l15 < 4;
#pragma unroll
      for (int r = 0; r < 4; ++r) {
        const float s = vip ? z[r] * scale : -1e30f;
        float m = s;
        m = fmaxf(m, __shfl_xor(m, 1));
        m = fmaxf(m, __shfl_xor(m, 2));
        m = fmaxf(m, __shfl_xor(m, 4));
        m = fmaxf(m, __shfl_xor(m, 8));
        const float p = __expf(s - m);
        float l = p;
        l += __shfl_xor(l, 1);
        l += __shfl_xor(l, 2);
        l += __shfl_xor(l, 4);
        l += __shfl_xor(l, 8);
        const int row = prow0 + r;
        *(bf16_t*)(pw + row * 256 + (((96 + l15) * 2) ^ ((row & 7) << 4))) =
            (bf16_t)(p * (1.f / l));
      }
    }

    f32x4 o[4] = {};
#pragma unroll
    for (int s = 0; s < 4; ++s) {
      const bf16x8 pa =
          ld16(pw + l15 * 256 + ((((s << 2) + hi) << 4) ^ ((l15 & 7) << 4)));
#pragma unroll
      for (int n = 0; n < 4; ++n) {
        const int d = (n << 4) + l15;
        const bf16x8 vb =
            ld16((char*)Vt_lds + d * 256 + ((((s << 2) + hi) << 4) ^ ((d & 7) << 4)));
        o[n] = __builtin_amdgcn_mfma_f32_16x16x32_bf16(pa, vb, o[n], 0, 0, 0);
      }
    }

    const long orow = qrow0 + ms * 16 + prow0;
#pragma unroll
    for (int n = 0; n < 4; ++n)
#pragma unroll
      for (int r = 0; r < 4; ++r)
        outp[(orow + r) * 1280 + kvcol + (n << 4) + l15] = (bf16_t)o[n][r];
  }
}

// ---------------------------------------------------------------------------
// prep: merged cvt_bf16 (blocks 0-40959) + weight transpose (40960-56319)
// + pack_enc with padding (56320-58367). Valid ip rows: 32 (=B*NT).
// ---------------------------------------------------------------------------
__global__ __launch_bounds__(256)
void prep(const float* __restrict__ hs, bf16_t* __restrict__ hsb,
          const float* __restrict__ Wq, const float* __restrict__ Wo,
          const float* __restrict__ Wk, const float* __restrict__ Wv,
          const float* __restrict__ Wki, const float* __restrict__ Wvi,
          bf16_t* __restrict__ Wq_t, bf16_t* __restrict__ Wo_t,
          bf16_t* __restrict__ Wkv_t, bf16_t* __restrict__ Wip_t,
          const float* __restrict__ enc, bf16_t* __restrict__ a_txt,
          bf16_t* __restrict__ a_ip)
{
  __shared__ float tile[32][33];
  const int bid = blockIdx.x, tid = threadIdx.x;

  if (bid < 40960) {                       // hs fp32 -> bf16 (41943040 elems)
    const long i = ((long)bid * 256 + tid) * 4;
    const float4 v = *(const float4*)(hs + i);
    bf16x4 r;
    r[0] = (bf16_t)v.x; r[1] = (bf16_t)v.y; r[2] = (bf16_t)v.z; r[3] = (bf16_t)v.w;
    *(bf16x4*)(hsb + i) = r;
  } else if (bid < 56320) {                // weight transpose+cvt (6 weights)
    const int idx = bid - 40960;
    const int z = idx / 2560, rem = idx % 2560;
    const int kx = rem & 63, ny = rem >> 6; // 64 k-tiles x 40 n-tiles
    const float* in;
    bf16_t* out;
    int K;
    switch (z) {
      case 0:  in = Wq;  out = Wq_t;                      K = 1280; break;
      case 1:  in = Wo;  out = Wo_t;                      K = 1280; break;
      case 2:  in = Wk;  out = Wkv_t;                     K = 2048; break;
      case 3:  in = Wv;  out = Wkv_t + (long)1280 * 2048; K = 2048; break;
      case 4:  in = Wki; out = Wip_t;                     K = 2048; break;
      default: in = Wvi; out = Wip_t + (long)1280 * 2048; K = 2048; break;
    }
    const int k0 = kx * 32, n0 = ny * 32;
    if (k0 < K) {
      const int tx = tid & 31, ty = tid >> 5;
      for (int i = ty; i < 32; i += 8)
        tile[i][tx] = in[(long)(k0 + i) * 1280 + n0 + tx];
      __syncthreads();
      for (int i = ty; i < 32; i += 8)
        out[(long)(n0 + i) * K + k0 + tx] = (bf16_t)tile[tx][i];
    }
  } else {                                 // encoder pack + zero-pad
    const long t4 = ((long)(bid - 56320) * 256 + tid) * 4;
    const long NTXT = 768L * 2048;
    bf16x4 r;
    r[0] = r[1] = r[2] = r[3] = (bf16_t)0.f;
    if (t4 < NTXT) {
      const int row = (int)(t4 >> 11), col = (int)(t4 & 2047);
      if (row < 640) {
        const int b = row / 80, j = row - b * 80;
        if (j < TXT_) {
          const float4 v = *(const float4*)(enc + (((long)(b * 81 + j)) << 11) + col);
          r[0] = (bf16_t)v.x; r[1] = (bf16_t)v.y; r[2] = (bf16_t)v.z; r[3] = (bf16_t)v.w;
        }
      }
      *(bf16x4*)(a_txt + t4) = r;
    } else {
      const long u = t4 - NTXT;
      const int row = (int)(u >> 11), col = (int)(u & 2047);
      if (row < 32) {                      // ONLY B*NT=32 valid ip rows
        const int b = row >> 2, j = row & 3;
        const float4 v = *(const float4*)(enc + (((long)(b * 81 + TXT_ + j)) << 11) + col);
        r[0] = (bf16_t)v.x; r[1] = (bf16_t)v.y; r[2] = (bf16_t)v.z; r[3] = (bf16_t)v.w;
      }
      *(bf16x4*)(a_ip + u) = r;
    }
  }
}

// ---------------------------------------------------------------------------
extern "C" void kernel_launch(void* const* d_in, const int* in_sizes, int n_in,
                              void* d_out, int out_size, void* d_ws, size_t ws_size,
                              hipStream_t stream)
{
  (void)in_sizes; (void)n_in; (void)out_size; (void)ws_size;
  const float* hs  = (const float*)d_in[0];
  const float* enc = (const float*)d_in[1];
  const float* Wq  = (const float*)d_in[2];
  const float* Wk  = (const float*)d_in[3];
  const float* Wv  = (const float*)d_in[4];
  const float* Wki = (const float*)d_in[5];
  const float* Wvi = (const float*)d_in[6];
  const float* Wo  = (const float*)d_in[7];
  const float* bo  = (const float*)d_in[8];

  char* ws = (char*)d_ws;
  size_t off = 0;
  auto alloc = [&](size_t bytes) {
    char* p = ws + off;
    off += (bytes + 255) & ~(size_t)255;
    return p;
  };
  bf16_t* buf1   = (bf16_t*)alloc(83886080);  // hs_bf16 (A of GEMM1 + residual of GEMM2)
  bf16_t* qb     = (bf16_t*)alloc(83886080);  // Q (32768 x 1280), attn in-place
  bf16_t* Wq_t   = (bf16_t*)alloc(3276800);
  bf16_t* Wo_t   = (bf16_t*)alloc(3276800);
  bf16_t* Wkv_t  = (bf16_t*)alloc(10485760);
  bf16_t* Wip_t  = (bf16_t*)alloc(10485760);
  bf16_t* a_txt  = (bf16_t*)alloc(3145728);   // 768 x 2048 (padded)
  bf16_t* a_ip   = (bf16_t*)alloc(1048576);   // 256 x 2048 (padded)
  bf16_t* kv_txt = (bf16_t*)alloc(3932160);   // 768 x 2560
  bf16_t* kv_ip  = (bf16_t*)alloc(1310720);   // 256 x 2560

  // one merged preprocessing dispatch
  prep<<<58368, 256, 0, stream>>>(hs, buf1, Wq, Wo, Wk, Wv, Wki, Wvi,
                                  Wq_t, Wo_t, Wkv_t, Wip_t, enc, a_txt, a_ip);

  // GEMM1 + K|V + Kip|Vip in one dispatch (680 blocks)
  gemm1_fused<<<680, 512, 0, stream>>>(buf1, Wq_t, qb,
                                       a_txt, Wkv_t, kv_txt,
                                       a_ip, Wip_t, kv_ip);

  // fused dual-softmax attention, in-place on qb
  attn_fused<<<dim3(16, 20, 8), 256, 0, stream>>>(qb, kv_txt, kv_ip, qb);

  // out = attn @ Wo + bo + residual(bf16)
  gemm2<<<640, 512, 0, stream>>>(qb, Wo_t, (float*)d_out, bo, buf1);
}